// Round 21
// baseline (499.745 us; speedup 1.0000x reference)
//
#include <hip/hip_runtime.h>
#include <hip/hip_fp16.h>

#define TDIM 512
#define FDIM 80

typedef _Float16 f16x8 __attribute__((ext_vector_type(8)));
typedef _Float16 f16x4 __attribute__((ext_vector_type(4)));
typedef _Float16 f16x2 __attribute__((ext_vector_type(2)));
typedef float f32x4 __attribute__((ext_vector_type(4)));

// ---------------- weight prep: fp32 HWIO [ky][kx][ci][co] -> fp16 [kk][co][ci] ----------------
__global__ __launch_bounds__(256) void k_prep_w(
    const float* __restrict__ wq, const float* __restrict__ wk,
    const float* __restrict__ wv, const float* __restrict__ wo,
    _Float16* __restrict__ wTq, _Float16* __restrict__ wTk,
    _Float16* __restrict__ wTv, _Float16* __restrict__ wTo)
{
  const int total = 3 * 36864 + 73728;
  for (int idx = blockIdx.x * 256 + threadIdx.x; idx < total; idx += gridDim.x * 256) {
    if (idx < 110592) {
      int sel = idx / 36864, r = idx - sel * 36864;      // [kk][co][ci], ci fastest
      int ci = r & 63, t2 = r >> 6, co = t2 & 63, kk = t2 >> 6;
      const float* src = (sel == 0) ? wq : (sel == 1) ? wk : wv;
      _Float16* dst = (sel == 0) ? wTq : (sel == 1) ? wTk : wTv;
      dst[r] = (_Float16)src[(kk * 64 + ci) * 64 + co];
    } else {
      int r = idx - 110592;                              // wo: ci 128
      int ci = r & 127, t2 = r >> 7, co = t2 & 63, kk = t2 >> 6;
      wTo[r] = (_Float16)wo[(kk * 128 + ci) * 64 + co];
    }
  }
}

// ---------------- 3x fused conv 3x3 64->64, t-PAIR blocks (512 thr) ----------------
// waves = (tsel 2) x (cH 2) x (fH 2): each wave does 32 channels (2 B-frags per A-read)
// over mt in {0,1,2} (fH=0) or {3,4} (fH=1). A-frag LDS reads per block: 720 -> 360.
__global__ __launch_bounds__(512) void k_conv_in3(
    const float* __restrict__ q, const float* __restrict__ k, const float* __restrict__ v,
    const float* __restrict__ wq, const float* __restrict__ wk, const float* __restrict__ wv,
    const _Float16* __restrict__ wTq, const _Float16* __restrict__ wTk, const _Float16* __restrict__ wTv,
    const float* __restrict__ bq, const float* __restrict__ bk, const float* __restrict__ bv,
    _Float16* __restrict__ yq, _Float16* __restrict__ yk, _Float16* __restrict__ yv)
{
  __shared__ __align__(16) _Float16 xs[328 * 72];  // [rr*82+fi][ci], rr=0..3 (t0-1..t0+2)
  const int bid = blockIdx.x;                      // 6144 = 3 sel x 2048
  const int sel = bid >> 11, rest = bid & 2047;
  const float* x = (sel == 0) ? q : (sel == 1) ? k : v;
  const float* w = (sel == 0) ? wq : (sel == 1) ? wk : wv;
  const _Float16* wT = (sel == 0) ? wTq : (sel == 1) ? wTk : wTv;
  const float* bias = (sel == 0) ? bq : (sel == 1) ? bk : bv;
  _Float16* y = (sel == 0) ? yq : (sel == 1) ? yk : yv;

  // XCD t-chunk remap: each XCD owns a contiguous 64-t chunk (32 pairs)
  const int xcd = rest & 7, i = rest >> 3;         // i 0..255
  const int b = i >> 5, tp = i & 31;
  const int t0 = (xcd << 6) | (tp << 1);           // even t
  const int tid = threadIdx.x;
  const int wvv = tid >> 6, ln = tid & 63;
  const int tsel = wvv >> 2;                       // 0: t0, 1: t0+1
  const int cH = (wvv >> 1) & 1;                   // channel half: 0..1
  const int fH = wvv & 1;                          // f range: 0 -> mt 0..2, 1 -> mt 3..4
  const int lr = ln & 15, lg = ln >> 4;
  const int c0 = cH * 32;
  const int mtBase = fH ? 3 : 0;
  const int mtN = fH ? 2 : 3;

  // batched staging: issue all 11 loads first (independent), then cvt+store
  float4 vb[11];
  #pragma unroll
  for (int kk = 0; kk < 11; kk++) {
    int idx = tid + (kk << 9);
    vb[kk] = make_float4(0.f, 0.f, 0.f, 0.f);
    if (idx < 5248) {                              // 328*16
      int r2 = idx >> 4, cq = idx & 15;
      int rr = r2 / 82, fi = r2 - rr * 82;
      int tt = t0 - 1 + rr, ff = fi - 1;
      if (tt >= 0 && tt < TDIM && ff >= 0 && ff < FDIM)
        vb[kk] = *reinterpret_cast<const float4*>(x + (((b * TDIM + tt) * FDIM + ff) << 6) + cq * 4);
    }
  }
  #pragma unroll
  for (int kk = 0; kk < 11; kk++) {
    int idx = tid + (kk << 9);
    if (idx < 5248) {
      int r2 = idx >> 4, cq = idx & 15;
      f16x4 h;
      h[0] = (_Float16)vb[kk].x; h[1] = (_Float16)vb[kk].y;
      h[2] = (_Float16)vb[kk].z; h[3] = (_Float16)vb[kk].w;
      *reinterpret_cast<f16x4*>(&xs[r2 * 72 + cq * 4]) = h;
    }
  }
  __syncthreads();

  const float bv0 = bias[c0 + lr];
  const float bv1 = bias[c0 + 16 + lr];
  f32x4 acc[3][2];
  #pragma unroll
  for (int m = 0; m < 3; m++)
    #pragma unroll
    for (int r = 0; r < 4; r++) { acc[m][0][r] = bv0; acc[m][1][r] = bv1; }

  for (int ky = 0; ky < 3; ky++) {
    #pragma unroll
    for (int kx = 0; kx < 3; kx++) {
      #pragma unroll
      for (int cc = 0; cc < 2; cc++) {
        f16x8 wf0, wf1;
        if (wT) {
          wf0 = *reinterpret_cast<const f16x8*>(
              wT + (((ky * 3 + kx) * 64 + c0 + lr) << 6) + cc * 32 + lg * 8);
          wf1 = *reinterpret_cast<const f16x8*>(
              wT + (((ky * 3 + kx) * 64 + c0 + 16 + lr) << 6) + cc * 32 + lg * 8);
        } else {
          const float* wp0 = w + ((ky * 3 + kx) * 64 + cc * 32 + lg * 8) * 64 + c0 + lr;
          const float* wp1 = wp0 + 16;
          #pragma unroll
          for (int j = 0; j < 8; j++) { wf0[j] = (_Float16)wp0[j * 64]; wf1[j] = (_Float16)wp1[j * 64]; }
        }
        #pragma unroll
        for (int m = 0; m < 3; m++) {
          if (m < mtN) {
            int mtA = mtBase + m;
            f16x8 af = *reinterpret_cast<const f16x8*>(
                &xs[((tsel + ky) * 82 + mtA * 16 + lr + kx) * 72 + cc * 32 + lg * 8]);
            acc[m][0] = __builtin_amdgcn_mfma_f32_16x16x32_f16(af, wf0, acc[m][0], 0, 0, 0);
            acc[m][1] = __builtin_amdgcn_mfma_f32_16x16x32_f16(af, wf1, acc[m][1], 0, 0, 0);
          }
        }
      }
    }
  }

  // epilogue: per-tsel bounce [64 c][88 f] through xs, then coalesced f16x8 rows
  __syncthreads();                   // all waves done reading xs
  _Float16* yt = xs + tsel * 5632;   // [64 c][88 f]
  #pragma unroll
  for (int cN = 0; cN < 2; cN++) {
    int c = c0 + cN * 16 + lr;
    #pragma unroll
    for (int m = 0; m < 3; m++) {
      if (m < mtN) {
        int mtA = mtBase + m;
        f16x4 h;
        #pragma unroll
        for (int r = 0; r < 4; r++) h[r] = (_Float16)acc[m][cN][r];
        *reinterpret_cast<f16x4*>(&yt[c * 88 + mtA * 16 + lg * 4]) = h;
      }
    }
  }
  __syncthreads();
  #pragma unroll
  for (int kk = 0; kk < 3; kk++) {
    int idx = tid + (kk << 9);
    if (idx < 1280) {                // 2 t x 64 c x 10 f8
      int ts = idx >= 640, r2 = idx - ts * 640;
      int cc = r2 / 10, f8 = r2 - cc * 10;
      *reinterpret_cast<f16x8*>(y + ((size_t)(b * 64 + cc) * TDIM + t0 + ts) * FDIM + f8 * 8) =
          *reinterpret_cast<const f16x8*>(&xs[ts * 5632 + cc * 88 + f8 * 8]);
    }
  }
}

// ---------------- freq attention (MFMA, 8 waves, Q-tile 128, fixed-max softmax, l via ones-row MFMA) ----------------
// CAT2 layout: [B][128][T][F]; freq writes channels 64..127 (its own contiguous plane)
__global__ __launch_bounds__(512) void k_attn_freq(
    const _Float16* __restrict__ XQ, const _Float16* __restrict__ XK,
    const _Float16* __restrict__ XV, _Float16* __restrict__ CAT)
{
  __shared__ __align__(16) _Float16 Ks[64 * 104];   // [m][k], cols 80..103 pad (zeroed once)
  __shared__ __align__(16) _Float16 Vt[96 * 72];    // [f][m]; rows 80..95 fixed (row80=1, rest 0)
  __shared__ __align__(16) _Float16 Pl[8 * 16 * 72];// per-wave P bounce [16 q][72], XOR-swizzled

  const int bid = blockIdx.x;                       // 2048 blocks
  const int x8 = bid & 7, kk = bid >> 3;            // kk 0..255
  const int jj = kk & 7, tl = (kk >> 3) & 3, cc8 = kk >> 5;
  const int bc = x8 + cc8 * 64 + jj * 8;            // bc % 8 == x8 (XCD-stable)
  const int b = bc >> 6, c = bc & 63;
  const int t0 = tl * 128;
  const int tid = threadIdx.x;
  const int w8 = tid >> 6, ln = tid & 63;
  const int lr = ln & 15, lg = ln >> 4;
  const float qscale = 0.1118033988749895f;         // 1/sqrt(80)
  const float MFIX = 4.0f;                          // fixed softmax shift

  const _Float16* Qg = XQ + (size_t)bc * 40960 + (size_t)t0 * 80;
  const _Float16* Kg = XK + (size_t)bc * 40960;
  const _Float16* Vg = XV + (size_t)bc * 40960;

  f16x8 qf[3];
  qf[0] = *reinterpret_cast<const f16x8*>(Qg + (w8 * 16 + lr) * 80 + lg * 8);
  qf[1] = *reinterpret_cast<const f16x8*>(Qg + (w8 * 16 + lr) * 80 + 32 + lg * 8);
  {
    f16x8 z;
    #pragma unroll
    for (int j = 0; j < 8; j++) z[j] = (_Float16)0.f;
    qf[2] = (lg < 2) ? *reinterpret_cast<const f16x8*>(Qg + (w8 * 16 + lr) * 80 + 64 + lg * 8) : z;
  }
  #pragma unroll
  for (int kc = 0; kc < 3; kc++)
    #pragma unroll
    for (int j = 0; j < 8; j++) qf[kc][j] = qf[kc][j] * (_Float16)qscale;

  if (tid < 192) {                                  // zero K pad cols 80..103 once
    int row = tid / 3, cw = tid - row * 3;
    f16x8 z;
    #pragma unroll
    for (int j = 0; j < 8; j++) z[j] = (_Float16)0.f;
    *reinterpret_cast<f16x8*>(&Ks[row * 104 + 80 + cw * 8]) = z;
  }
  if (tid < 144) {                                  // Vt rows 80..95: row 80 = 1.0, rest 0 (once)
    int rr = tid / 9, cw = tid - rr * 9;
    int row = 80 + rr;
    f16x8 v;
    #pragma unroll
    for (int j = 0; j < 8; j++) v[j] = (row == 80) ? (_Float16)1.f : (_Float16)0.f;
    *reinterpret_cast<f16x8*>(&Vt[row * 72 + cw * 8]) = v;
  }

  const int vm = tid & 63;
  f16x8 kreg0, kreg1;
  f16x2 vreg[5];
  {
    int i0 = tid, r0 = i0 / 10, w0 = i0 - r0 * 10;
    kreg0 = *reinterpret_cast<const f16x8*>(Kg + r0 * 80 + w0 * 8);
    if (tid < 128) {
      int i1 = tid + 512, r1 = i1 / 10, w1 = i1 - r1 * 10;
      kreg1 = *reinterpret_cast<const f16x8*>(Kg + r1 * 80 + w1 * 8);
    }
    #pragma unroll
    for (int s = 0; s < 5; s++)
      vreg[s] = *reinterpret_cast<const f16x2*>(Vg + vm * 80 + (w8 + 8 * s) * 2);
  }

  f32x4 O[6];                        // [0..4]: f-blocks; [5]: ones-row block (col 0 = row-sum l)
  #pragma unroll
  for (int ft = 0; ft < 6; ft++)
    #pragma unroll
    for (int r = 0; r < 4; r++) O[ft][r] = 0.f;

  for (int kt = 0; kt < 8; kt++) {
    __syncthreads();                 // prior compute done reading LDS
    {
      int i0 = tid, r0 = i0 / 10, w0 = i0 - r0 * 10;
      *reinterpret_cast<f16x8*>(&Ks[r0 * 104 + w0 * 8]) = kreg0;
      if (tid < 128) {
        int i1 = tid + 512, r1 = i1 / 10, w1 = i1 - r1 * 10;
        *reinterpret_cast<f16x8*>(&Ks[r1 * 104 + w1 * 8]) = kreg1;
      }
      #pragma unroll
      for (int s = 0; s < 5; s++) {
        int f2 = (w8 + 8 * s) * 2;
        Vt[f2 * 72 + vm]       = vreg[s][0];
        Vt[(f2 + 1) * 72 + vm] = vreg[s][1];
      }
    }
    if (kt < 7) {
      const _Float16* Kn = Kg + (kt + 1) * 64 * 80;
      const _Float16* Vn = Vg + (kt + 1) * 64 * 80;
      int i0 = tid, r0 = i0 / 10, w0 = i0 - r0 * 10;
      kreg0 = *reinterpret_cast<const f16x8*>(Kn + r0 * 80 + w0 * 8);
      if (tid < 128) {
        int i1 = tid + 512, r1 = i1 / 10, w1 = i1 - r1 * 10;
        kreg1 = *reinterpret_cast<const f16x8*>(Kn + r1 * 80 + w1 * 8);
      }
      #pragma unroll
      for (int s = 0; s < 5; s++)
        vreg[s] = *reinterpret_cast<const f16x2*>(Vn + vm * 80 + (w8 + 8 * s) * 2);
    }
    __syncthreads();                 // LDS tile ready

    f32x4 S[4];
    #pragma unroll
    for (int ms = 0; ms < 4; ms++)
      #pragma unroll
      for (int r = 0; r < 4; r++) S[ms][r] = 0.f;
    __builtin_amdgcn_s_setprio(1);
    #pragma unroll
    for (int kc = 0; kc < 3; kc++) {
      #pragma unroll
      for (int ms = 0; ms < 4; ms++) {
        f16x8 kf = *reinterpret_cast<const f16x8*>(&Ks[(ms * 16 + lr) * 104 + kc * 32 + lg * 8]);
        S[ms] = __builtin_amdgcn_mfma_f32_16x16x32_f16(qf[kc], kf, S[ms], 0, 0, 0);
      }
    }
    __builtin_amdgcn_s_setprio(0);

    // fixed-max softmax numerator: p = exp(s - MFIX); no reductions, no rescale
    _Float16* pw = &Pl[w8 * 16 * 72];
    #pragma unroll
    for (int r = 0; r < 4; r++) {
      int row = lg * 4 + r;
      #pragma unroll
      for (int ms = 0; ms < 4; ms++)
        pw[row * 72 + ((ms * 16 + lr) ^ (lg << 3))] = (_Float16)__expf(S[ms][r] - MFIX);
    }
    asm volatile("s_waitcnt lgkmcnt(0)" ::: "memory");
    const int sx = (lg ^ ((lr >> 2) & 3)) * 8;
    f16x8 pf0 = *reinterpret_cast<const f16x8*>(&pw[lr * 72 + sx]);
    f16x8 pf1 = *reinterpret_cast<const f16x8*>(&pw[lr * 72 + 32 + sx]);

    __builtin_amdgcn_s_setprio(1);
    #pragma unroll
    for (int ft = 0; ft < 6; ft++) {
      f16x8 vf0 = *reinterpret_cast<const f16x8*>(&Vt[(ft * 16 + lr) * 72 + lg * 8]);
      f16x8 vf1 = *reinterpret_cast<const f16x8*>(&Vt[(ft * 16 + lr) * 72 + 32 + lg * 8]);
      O[ft] = __builtin_amdgcn_mfma_f32_16x16x32_f16(pf0, vf0, O[ft], 0, 0, 0);
      O[ft] = __builtin_amdgcn_mfma_f32_16x16x32_f16(pf1, vf1, O[ft], 0, 0, 0);
    }
    __builtin_amdgcn_s_setprio(0);
  }

  // epilogue: l for row lg*4+r sits in lane (lg*16 + 0), component r
  float inv[4];
  #pragma unroll
  for (int r = 0; r < 4; r++) {
    float l = __shfl(O[5][r], lg << 4);
    inv[r] = 1.f / l;
  }
  #pragma unroll
  for (int r = 0; r < 4; r++) {
    int t = t0 + w8 * 16 + lg * 4 + r;
    size_t base = ((size_t)(b * 128 + 64 + c) * TDIM + t) * FDIM;
    #pragma unroll
    for (int ft = 0; ft < 5; ft++)
      CAT[base + ft * 16 + lr] = (_Float16)(O[ft][r] * inv[r]);
  }
}

// ---------------- time attention via MFMA: per (b,c); writes CAT2 channel c plane ----------------
__global__ __launch_bounds__(256) void k_attn_time(
    const _Float16* __restrict__ XQ, const _Float16* __restrict__ XK,
    const _Float16* __restrict__ XV, _Float16* __restrict__ CAT)
{
  __shared__ __align__(16) char smem[70400];
  _Float16* Qt  = (_Float16*)smem;              // [80][136] phase1
  _Float16* Kt  = Qt + 80 * 136;                // [80][136]
  float*    Sld = (float*)(smem + 43520);       // [80][84] fp32 scores
  _Float16* Pld = (_Float16*)smem;              // [80][104] phase2 (aliases Qt, post-barrier)

  const int bid = blockIdx.x;                   // 512 blocks = (b,c)
  const int b = bid >> 6, c = bid & 63;
  const int tid = threadIdx.x;
  const int wv = tid >> 6, ln = tid & 63;
  const int lr = ln & 15, lg = ln >> 4;
  const float tscale = 0.04419417382415922f;    // 1/sqrt(512)

  const _Float16* Qg = XQ + (size_t)bid * 40960;
  const _Float16* Kg = XK + (size_t)bid * 40960;
  const _Float16* Vg = XV + (size_t)bid * 40960;

  f32x4 sacc[7];
  #pragma unroll
  for (int i = 0; i < 7; i++)
    #pragma unroll
    for (int r = 0; r < 4; r++) sacc[i][r] = 0.f;

  for (int tc = 0; tc < 4; tc++) {
    __syncthreads();
    for (int idx = tid; idx < 640; idx += 256) {
      int t2 = idx / 10, f8 = idx - t2 * 10;
      int tg = tc * 128 + t2 * 2;
      f16x8 qa = *reinterpret_cast<const f16x8*>(Qg + (size_t)tg * 80 + f8 * 8);
      f16x8 qb = *reinterpret_cast<const f16x8*>(Qg + (size_t)(tg + 1) * 80 + f8 * 8);
      f16x8 ka = *reinterpret_cast<const f16x8*>(Kg + (size_t)tg * 80 + f8 * 8);
      f16x8 kb = *reinterpret_cast<const f16x8*>(Kg + (size_t)(tg + 1) * 80 + f8 * 8);
      #pragma unroll
      for (int j = 0; j < 8; j++) {
        int f = f8 * 8 + j;
        f16x2 qp; qp[0] = qa[j]; qp[1] = qb[j];
        f16x2 kp; kp[0] = ka[j]; kp[1] = kb[j];
        *reinterpret_cast<f16x2*>(&Qt[f * 136 + t2 * 2]) = qp;
        *reinterpret_cast<f16x2*>(&Kt[f * 136 + t2 * 2]) = kp;
      }
    }
    __syncthreads();
    #pragma unroll
    for (int i = 0; i < 7; i++) {
      int ti = wv * 7 + i;
      int te = ti < 25 ? ti : 24;
      int mi = te / 5, ni = te - mi * 5;
      #pragma unroll
      for (int kc = 0; kc < 4; kc++) {
        f16x8 aq = *reinterpret_cast<const f16x8*>(&Qt[(mi * 16 + lr) * 136 + kc * 32 + lg * 8]);
        f16x8 bk = *reinterpret_cast<const f16x8*>(&Kt[(ni * 16 + lr) * 136 + kc * 32 + lg * 8]);
        sacc[i] = __builtin_amdgcn_mfma_f32_16x16x32_f16(aq, bk, sacc[i], 0, 0, 0);
      }
    }
  }
  #pragma unroll
  for (int i = 0; i < 7; i++) {
    int ti = wv * 7 + i;
    if (ti < 25) {
      int mi = ti / 5, ni = ti - mi * 5;
      #pragma unroll
      for (int r = 0; r < 4; r++)
        Sld[(mi * 16 + lg * 4 + r) * 84 + ni * 16 + lr] = sacc[i][r] * tscale;
    }
  }
  __syncthreads();

  {
    const int fy = tid >> 4, gx = tid & 15;
    #pragma unroll
    for (int pass = 0; pass < 5; pass++) {
      int row = pass * 16 + fy;
      float s[5];
      #pragma unroll
      for (int j = 0; j < 5; j++) s[j] = Sld[row * 84 + gx + 16 * j];
      float mx = fmaxf(fmaxf(fmaxf(s[0], s[1]), fmaxf(s[2], s[3])), s[4]);
      #pragma unroll
      for (int sh = 1; sh < 16; sh <<= 1) mx = fmaxf(mx, __shfl_xor(mx, sh, 16));
      float e[5]; float ls = 0.f;
      #pragma unroll
      for (int j = 0; j < 5; j++) { e[j] = __expf(s[j] - mx); ls += e[j]; }
      #pragma unroll
      for (int sh = 1; sh < 16; sh <<= 1) ls += __shfl_xor(ls, sh, 16);
      float inv = 1.f / ls;
      #pragma unroll
      for (int j = 0; j < 5; j++)
        Pld[row * 104 + gx + 16 * j] = (_Float16)(e[j] * inv);
    }
    for (int idx = tid; idx < 240; idx += 256) {
      int row = idx / 3, cw = idx - row * 3;
      f16x8 z;
      #pragma unroll
      for (int j = 0; j < 8; j++) z[j] = (_Float16)0.f;
      *reinterpret_cast<f16x8*>(&Pld[row * 104 + 80 + cw * 8]) = z;
    }
  }
  __syncthreads();

  f16x8 pa[5][3];
  #pragma unroll
  for (int mi = 0; mi < 5; mi++)
    #pragma unroll
    for (int kc = 0; kc < 3; kc++)
      pa[mi][kc] = *reinterpret_cast<const f16x8*>(&Pld[(mi * 16 + lr) * 104 + kc * 32 + lg * 8]);

  _Float16* Ow = (_Float16*)(smem + 43520) + wv * (16 * 88);  // per-wave [16 t][88 f] (Sld dead)
  const size_t chbase = (size_t)(b * 128 + c) * TDIM * FDIM;

  #pragma unroll
  for (int j = 0; j < 8; j++) {
    int nt = wv * 8 + j;
    f16x8 vf[3];
    #pragma unroll
    for (int kc = 0; kc < 3; kc++) {
      if (kc < 2) {
        vf[kc] = *reinterpret_cast<const f16x8*>(Vg + (size_t)(nt * 16 + lr) * 80 + kc * 32 + lg * 8);
      } else {
        f16x8 z;
        #pragma unroll
        for (int qq = 0; qq < 8; qq++) z[qq] = (_Float16)0.f;
        vf[kc] = (lg < 2) ? *reinterpret_cast<const f16x8*>(Vg + (size_t)(nt * 16 + lr) * 80 + 64 + lg * 8) : z;
      }
    }
    f32x4 oacc[5];
    #pragma unroll
    for (int mi = 0; mi < 5; mi++)
      #pragma unroll
      for (int r = 0; r < 4; r++) oacc[mi][r] = 0.f;
    #pragma unroll
    for (int mi = 0; mi < 5; mi++)
      #pragma unroll
      for (int kc = 0; kc < 3; kc++)
        oacc[mi] = __builtin_amdgcn_mfma_f32_16x16x32_f16(pa[mi][kc], vf[kc], oacc[mi], 0, 0, 0);

    #pragma unroll
    for (int mi = 0; mi < 5; mi++) {
      f16x4 h;
      #pragma unroll
      for (int r = 0; r < 4; r++) h[r] = (_Float16)oacc[mi][r];
      *reinterpret_cast<f16x4*>(&Ow[lr * 88 + mi * 16 + lg * 4]) = h;
    }
    asm volatile("s_waitcnt lgkmcnt(0)" ::: "memory");
    size_t basec = chbase + (size_t)(nt * 16) * FDIM;
    #pragma unroll
    for (int kk2 = 0; kk2 < 3; kk2++) {
      int idx = ln + (kk2 << 6);
      if (idx < 160) {
        int tl2 = idx / 10, f8 = idx - tl2 * 10;
        *reinterpret_cast<f16x8*>(CAT + basec + tl2 * 80 + f8 * 8) =
            *reinterpret_cast<const f16x8*>(&Ow[tl2 * 88 + f8 * 8]);
      }
    }
  }
}

// ---------------- conv 3x3 128->64, t-PAIR + two-phase ci (512 thr), batched staging ----------------
__global__ __launch_bounds__(512) void k_conv_out(
    const _Float16* __restrict__ x, const float* __restrict__ w,
    const _Float16* __restrict__ wT,
    const float* __restrict__ bias, float* __restrict__ out)
{
  __shared__ __align__(16) _Float16 xs[328 * 72];   // [rr*82+fi][ci 64 of current phase]
  const int bid = blockIdx.x;                       // 2048
  const int xcd = bid & 7, i = bid >> 3;            // i 0..255
  const int b = i >> 5, tp = i & 31;
  const int t0 = (xcd << 6) | (tp << 1);
  const int tid = threadIdx.x;
  const int wvv = tid >> 6, ln = tid & 63;
  const int tsel = wvv >> 2;                        // 0: t0, 1: t0+1
  const int lr = ln & 15, lg = ln >> 4;
  const int c0 = (wvv & 3) * 16;
  const int t = t0 + tsel;

  float bv = bias[c0 + lr];
  f32x4 acc[5];
  #pragma unroll
  for (int mt = 0; mt < 5; mt++)
    #pragma unroll
    for (int r = 0; r < 4; r++) acc[mt][r] = bv;

  const _Float16* xb = x + (size_t)b * 128 * TDIM * FDIM;

  for (int h = 0; h < 2; h++) {
    __syncthreads();                                // prior phase's reads complete
    {
      int cch = tid & 63, sk = tid >> 6;            // sk 0..7
      int rr = sk >> 1, side = sk & 1;
      xs[(rr * 82 + side * 81) * 72 + cch] = (_Float16)0.f;
    }
    f16x8 hb[5];
    #pragma unroll
    for (int kk = 0; kk < 5; kk++) {
      int idx = tid + (kk << 9);                    // 0..2559
      int cch = idx & 63, rest = idx >> 6;          // rest 0..39
      int rr = rest / 10, f8 = rest - rr * 10;
      int tt = t0 - 1 + rr;
      #pragma unroll
      for (int j = 0; j < 8; j++) hb[kk][j] = (_Float16)0.f;
      if (tt >= 0 && tt < TDIM)
        hb[kk] = *reinterpret_cast<const f16x8*>(xb + ((size_t)(h * 64 + cch) * TDIM + tt) * FDIM + f8 * 8);
    }
    #pragma unroll
    for (int kk = 0; kk < 5; kk++) {
      int idx = tid + (kk << 9);
      int cch = idx & 63, rest = idx >> 6;
      int rr = rest / 10, f8 = rest - rr * 10;
      #pragma unroll
      for (int j = 0; j < 8; j++)
        xs[(rr * 82 + f8 * 8 + j + 1) * 72 + cch] = hb[kk][j];
    }
    __syncthreads();

    for (int ky = 0; ky < 3; ky++) {
      const int rr = tsel + ky;                     // row t+ky-1 lives at slot rr
      f16x8 wf[3][2];
      #pragma unroll
      for (int kx = 0; kx < 3; kx++)
        #pragma unroll
        for (int cc = 0; cc < 2; cc++) {
          if (wT) {
            wf[kx][cc] = *reinterpret_cast<const f16x8*>(
                wT + (((ky * 3 + kx) * 64 + c0 + lr) << 7) + h * 64 + cc * 32 + lg * 8);
          } else {
            const float* wp = w + ((ky * 3 + kx) * 128 + h * 64 + cc * 32 + lg * 8) * 64 + c0 + lr;
            #pragma unroll
            for (int j = 0; j < 8; j++) wf[kx][cc][j] = (_Float16)wp[j * 64];
          }
        }
      #pragma unroll
      for (int mt = 0; mt < 5; mt++) {
        #pragma unroll
        for (int kx = 0; kx < 3; kx++) {
          const _Float16* ap = &xs[(rr * 82 + mt * 16 + lr + kx) * 72];
          #pragma unroll
          for (int cc = 0; cc < 2; cc++) {
            f16x8 af = *reinterpret_cast<const f16x8*>(ap + cc * 32 + lg * 8);
            acc[mt] = __builtin_amdgcn_mfma_f32_16x16x32_f16(af, wf[kx][cc], acc[mt], 0, 0, 0);
          }
        }
      }
    }
  }

  const int c = c0 + lr;
  #pragma unroll
  for (int mt = 0; mt < 5; mt++) {
    #pragma unroll
    for (int r = 0; r < 4; r++) {
      int f = mt * 16 + lg * 4 + r;
      out[((size_t)(b * TDIM + t) * FDIM + f) * 64 + c] = acc[mt][r];
    }
  }
}

extern "C" void kernel_launch(void* const* d_in, const int* in_sizes, int n_in,
                              void* d_out, int out_size, void* d_ws, size_t ws_size,
                              hipStream_t stream)
{
  const float* q  = (const float*)d_in[0];
  const float* k  = (const float*)d_in[1];
  const float* v  = (const float*)d_in[2];
  const float* wq = (const float*)d_in[3];
  const float* bq = (const float*)d_in[4];
  const float* wk = (const float*)d_in[5];
  const float* bk = (const float*)d_in[6];
  const float* wv = (const float*)d_in[7];
  const float* bv = (const float*)d_in[8];
  const float* wo = (const float*)d_in[9];
  const float* bo = (const float*)d_in[10];

  const size_t PLANE = (size_t)8 * 64 * 512 * 80;   // 20,971,520 elements
  _Float16* XQh  = (_Float16*)d_ws;
  _Float16* XKh  = XQh + PLANE;
  _Float16* CATh = XKh + PLANE;                     // CAT2 [B][128][T][F] fp16
  _Float16* XVh  = (_Float16*)d_out;                // dead before k_conv_out writes

  // optional fp16-transposed weights after CAT (needs 368 KB beyond the 168 MB base)
  _Float16* WT = CATh + 2 * PLANE;
  const size_t need = (4 * PLANE + 184320) * sizeof(_Float16);
  const bool useWT = (ws_size >= need);
  _Float16* wTq = useWT ? WT : nullptr;             // 36864 halves each
  _Float16* wTk = useWT ? WT + 36864 : nullptr;
  _Float16* wTv = useWT ? WT + 73728 : nullptr;
  _Float16* wTo = useWT ? WT + 110592 : nullptr;    // 73728 halves

  if (useWT)
    hipLaunchKernelGGL(k_prep_w, dim3(180), dim3(256), 0, stream,
                       wq, wk, wv, wo, wTq, wTk, wTv, wTo);

  hipLaunchKernelGGL(k_conv_in3, dim3(6144), dim3(512), 0, stream,
                     q, k, v, wq, wk, wv, wTq, wTk, wTv, bq, bk, bv, XQh, XKh, XVh);
  hipLaunchKernelGGL(k_attn_freq, dim3(2048), dim3(512), 0, stream, XQh, XKh, XVh, CATh);
  hipLaunchKernelGGL(k_attn_time, dim3(512), dim3(256), 0, stream, XQh, XKh, XVh, CATh);
  hipLaunchKernelGGL(k_conv_out, dim3(2048), dim3(512), 0, stream, CATh, wo, wTo, bo, (float*)d_out);
}

// Round 22
// 393.229 us; speedup vs baseline: 1.2709x; 1.2709x over previous
//
#include <hip/hip_runtime.h>
#include <hip/hip_fp16.h>

#define TDIM 512
#define FDIM 80

typedef _Float16 f16x8 __attribute__((ext_vector_type(8)));
typedef _Float16 f16x4 __attribute__((ext_vector_type(4)));
typedef _Float16 f16x2 __attribute__((ext_vector_type(2)));
typedef float f32x4 __attribute__((ext_vector_type(4)));

// ---------------- weight prep: fp32 HWIO [ky][kx][ci][co] -> fp16 [kk][co][ci] ----------------
__global__ __launch_bounds__(256) void k_prep_w(
    const float* __restrict__ wq, const float* __restrict__ wk,
    const float* __restrict__ wv, const float* __restrict__ wo,
    _Float16* __restrict__ wTq, _Float16* __restrict__ wTk,
    _Float16* __restrict__ wTv, _Float16* __restrict__ wTo)
{
  const int total = 3 * 36864 + 73728;
  for (int idx = blockIdx.x * 256 + threadIdx.x; idx < total; idx += gridDim.x * 256) {
    if (idx < 110592) {
      int sel = idx / 36864, r = idx - sel * 36864;      // [kk][co][ci], ci fastest
      int ci = r & 63, t2 = r >> 6, co = t2 & 63, kk = t2 >> 6;
      const float* src = (sel == 0) ? wq : (sel == 1) ? wk : wv;
      _Float16* dst = (sel == 0) ? wTq : (sel == 1) ? wTk : wTv;
      dst[r] = (_Float16)src[(kk * 64 + ci) * 64 + co];
    } else {
      int r = idx - 110592;                              // wo: ci 128
      int ci = r & 127, t2 = r >> 7, co = t2 & 63, kk = t2 >> 6;
      wTo[r] = (_Float16)wo[(kk * 128 + ci) * 64 + co];
    }
  }
}

// ---------------- 3x fused conv 3x3 64->64, t-PAIR blocks (512 thr), batched staging ----------------
// waves 0-3 compute t0, waves 4-7 compute t0+1; rows t0-1..t0+2 staged once.  (R18 proven version)
__global__ __launch_bounds__(512) void k_conv_in3(
    const float* __restrict__ q, const float* __restrict__ k, const float* __restrict__ v,
    const float* __restrict__ wq, const float* __restrict__ wk, const float* __restrict__ wv,
    const _Float16* __restrict__ wTq, const _Float16* __restrict__ wTk, const _Float16* __restrict__ wTv,
    const float* __restrict__ bq, const float* __restrict__ bk, const float* __restrict__ bv,
    _Float16* __restrict__ yq, _Float16* __restrict__ yk, _Float16* __restrict__ yv)
{
  __shared__ __align__(16) _Float16 xs[328 * 72];  // [rr*82+fi][ci], rr=0..3 (t0-1..t0+2)
  const int bid = blockIdx.x;                      // 6144 = 3 sel x 2048
  const int sel = bid >> 11, rest = bid & 2047;
  const float* x = (sel == 0) ? q : (sel == 1) ? k : v;
  const float* w = (sel == 0) ? wq : (sel == 1) ? wk : wv;
  const _Float16* wT = (sel == 0) ? wTq : (sel == 1) ? wTk : wTv;
  const float* bias = (sel == 0) ? bq : (sel == 1) ? bk : bv;
  _Float16* y = (sel == 0) ? yq : (sel == 1) ? yk : yv;

  // XCD t-chunk remap: each XCD owns a contiguous 64-t chunk (32 pairs)
  const int xcd = rest & 7, i = rest >> 3;         // i 0..255
  const int b = i >> 5, tp = i & 31;
  const int t0 = (xcd << 6) | (tp << 1);           // even t
  const int tid = threadIdx.x;
  const int wvv = tid >> 6, ln = tid & 63;
  const int tsel = wvv >> 2;                       // 0: t0, 1: t0+1
  const int lr = ln & 15, lg = ln >> 4;
  const int c0 = (wvv & 3) * 16;

  // batched staging: issue all 11 loads first (independent), then cvt+store
  float4 vb[11];
  #pragma unroll
  for (int kk = 0; kk < 11; kk++) {
    int idx = tid + (kk << 9);
    vb[kk] = make_float4(0.f, 0.f, 0.f, 0.f);
    if (idx < 5248) {                              // 328*16
      int r2 = idx >> 4, cq = idx & 15;
      int rr = r2 / 82, fi = r2 - rr * 82;
      int tt = t0 - 1 + rr, ff = fi - 1;
      if (tt >= 0 && tt < TDIM && ff >= 0 && ff < FDIM)
        vb[kk] = *reinterpret_cast<const float4*>(x + (((b * TDIM + tt) * FDIM + ff) << 6) + cq * 4);
    }
  }
  #pragma unroll
  for (int kk = 0; kk < 11; kk++) {
    int idx = tid + (kk << 9);
    if (idx < 5248) {
      int r2 = idx >> 4, cq = idx & 15;
      f16x4 h;
      h[0] = (_Float16)vb[kk].x; h[1] = (_Float16)vb[kk].y;
      h[2] = (_Float16)vb[kk].z; h[3] = (_Float16)vb[kk].w;
      *reinterpret_cast<f16x4*>(&xs[r2 * 72 + cq * 4]) = h;
    }
  }
  __syncthreads();

  float bvv = bias[c0 + lr];
  f32x4 acc[5];
  #pragma unroll
  for (int mt = 0; mt < 5; mt++)
    #pragma unroll
    for (int r = 0; r < 4; r++) acc[mt][r] = bvv;

  for (int ky = 0; ky < 3; ky++) {
    f16x8 wf[3][2];
    #pragma unroll
    for (int kx = 0; kx < 3; kx++)
      #pragma unroll
      for (int cc = 0; cc < 2; cc++) {
        if (wT) {
          wf[kx][cc] = *reinterpret_cast<const f16x8*>(
              wT + (((ky * 3 + kx) * 64 + c0 + lr) << 6) + cc * 32 + lg * 8);
        } else {
          const float* wp = w + ((ky * 3 + kx) * 64 + cc * 32 + lg * 8) * 64 + c0 + lr;
          #pragma unroll
          for (int j = 0; j < 8; j++) wf[kx][cc][j] = (_Float16)wp[j * 64];
        }
      }
    #pragma unroll
    for (int mt = 0; mt < 5; mt++) {
      #pragma unroll
      for (int kx = 0; kx < 3; kx++) {
        const _Float16* ap = &xs[((tsel + ky) * 82 + mt * 16 + lr + kx) * 72];
        #pragma unroll
        for (int cc = 0; cc < 2; cc++) {
          f16x8 af = *reinterpret_cast<const f16x8*>(ap + cc * 32 + lg * 8);
          acc[mt] = __builtin_amdgcn_mfma_f32_16x16x32_f16(af, wf[kx][cc], acc[mt], 0, 0, 0);
        }
      }
    }
  }

  // epilogue: per-tsel bounce [64 c][88 f] through xs, then coalesced f16x8 rows
  __syncthreads();                   // all waves done reading xs
  _Float16* yt = xs + tsel * 5632;   // [64 c][88 f]
  const int c = c0 + lr;
  #pragma unroll
  for (int mt = 0; mt < 5; mt++) {
    f16x4 h;
    #pragma unroll
    for (int r = 0; r < 4; r++) h[r] = (_Float16)acc[mt][r];
    *reinterpret_cast<f16x4*>(&yt[c * 88 + mt * 16 + lg * 4]) = h;
  }
  __syncthreads();
  #pragma unroll
  for (int kk = 0; kk < 3; kk++) {
    int idx = tid + (kk << 9);
    if (idx < 1280) {                // 2 t x 64 c x 10 f8
      int ts = idx >= 640, r2 = idx - ts * 640;
      int cc = r2 / 10, f8 = r2 - cc * 10;
      *reinterpret_cast<f16x8*>(y + ((size_t)(b * 64 + cc) * TDIM + t0 + ts) * FDIM + f8 * 8) =
          *reinterpret_cast<const f16x8*>(&xs[ts * 5632 + cc * 88 + f8 * 8]);
    }
  }
}

// ---------------- freq attention (MFMA, 8 waves, Q-tile 128, fixed-max softmax, l via ones-row MFMA) ----------------
// CAT2 layout: [B][128][T][F]; freq writes channels 64..127 (its own contiguous plane)
__global__ __launch_bounds__(512) void k_attn_freq(
    const _Float16* __restrict__ XQ, const _Float16* __restrict__ XK,
    const _Float16* __restrict__ XV, _Float16* __restrict__ CAT)
{
  __shared__ __align__(16) _Float16 Ks[64 * 104];   // [m][k], cols 80..103 pad (zeroed once)
  __shared__ __align__(16) _Float16 Vt[96 * 72];    // [f][m]; rows 80..95 fixed (row80=1, rest 0)
  __shared__ __align__(16) _Float16 Pl[8 * 16 * 72];// per-wave P bounce [16 q][72], XOR-swizzled

  const int bid = blockIdx.x;                       // 2048 blocks
  const int x8 = bid & 7, kk = bid >> 3;            // kk 0..255
  const int jj = kk & 7, tl = (kk >> 3) & 3, cc8 = kk >> 5;
  const int bc = x8 + cc8 * 64 + jj * 8;            // bc % 8 == x8 (XCD-stable)
  const int b = bc >> 6, c = bc & 63;
  const int t0 = tl * 128;
  const int tid = threadIdx.x;
  const int w8 = tid >> 6, ln = tid & 63;
  const int lr = ln & 15, lg = ln >> 4;
  const float qscale = 0.1118033988749895f;         // 1/sqrt(80)
  const float MFIX = 4.0f;                          // fixed softmax shift

  const _Float16* Qg = XQ + (size_t)bc * 40960 + (size_t)t0 * 80;
  const _Float16* Kg = XK + (size_t)bc * 40960;
  const _Float16* Vg = XV + (size_t)bc * 40960;

  f16x8 qf[3];
  qf[0] = *reinterpret_cast<const f16x8*>(Qg + (w8 * 16 + lr) * 80 + lg * 8);
  qf[1] = *reinterpret_cast<const f16x8*>(Qg + (w8 * 16 + lr) * 80 + 32 + lg * 8);
  {
    f16x8 z;
    #pragma unroll
    for (int j = 0; j < 8; j++) z[j] = (_Float16)0.f;
    qf[2] = (lg < 2) ? *reinterpret_cast<const f16x8*>(Qg + (w8 * 16 + lr) * 80 + 64 + lg * 8) : z;
  }
  #pragma unroll
  for (int kc = 0; kc < 3; kc++)
    #pragma unroll
    for (int j = 0; j < 8; j++) qf[kc][j] = qf[kc][j] * (_Float16)qscale;

  if (tid < 192) {                                  // zero K pad cols 80..103 once
    int row = tid / 3, cw = tid - row * 3;
    f16x8 z;
    #pragma unroll
    for (int j = 0; j < 8; j++) z[j] = (_Float16)0.f;
    *reinterpret_cast<f16x8*>(&Ks[row * 104 + 80 + cw * 8]) = z;
  }
  if (tid < 144) {                                  // Vt rows 80..95: row 80 = 1.0, rest 0 (once)
    int rr = tid / 9, cw = tid - rr * 9;
    int row = 80 + rr;
    f16x8 v;
    #pragma unroll
    for (int j = 0; j < 8; j++) v[j] = (row == 80) ? (_Float16)1.f : (_Float16)0.f;
    *reinterpret_cast<f16x8*>(&Vt[row * 72 + cw * 8]) = v;
  }

  const int vm = tid & 63;
  f16x8 kreg0, kreg1;
  f16x2 vreg[5];
  {
    int i0 = tid, r0 = i0 / 10, w0 = i0 - r0 * 10;
    kreg0 = *reinterpret_cast<const f16x8*>(Kg + r0 * 80 + w0 * 8);
    if (tid < 128) {
      int i1 = tid + 512, r1 = i1 / 10, w1 = i1 - r1 * 10;
      kreg1 = *reinterpret_cast<const f16x8*>(Kg + r1 * 80 + w1 * 8);
    }
    #pragma unroll
    for (int s = 0; s < 5; s++)
      vreg[s] = *reinterpret_cast<const f16x2*>(Vg + vm * 80 + (w8 + 8 * s) * 2);
  }

  f32x4 O[6];                        // [0..4]: f-blocks; [5]: ones-row block (col 0 = row-sum l)
  #pragma unroll
  for (int ft = 0; ft < 6; ft++)
    #pragma unroll
    for (int r = 0; r < 4; r++) O[ft][r] = 0.f;

  for (int kt = 0; kt < 8; kt++) {
    __syncthreads();                 // prior compute done reading LDS
    {
      int i0 = tid, r0 = i0 / 10, w0 = i0 - r0 * 10;
      *reinterpret_cast<f16x8*>(&Ks[r0 * 104 + w0 * 8]) = kreg0;
      if (tid < 128) {
        int i1 = tid + 512, r1 = i1 / 10, w1 = i1 - r1 * 10;
        *reinterpret_cast<f16x8*>(&Ks[r1 * 104 + w1 * 8]) = kreg1;
      }
      #pragma unroll
      for (int s = 0; s < 5; s++) {
        int f2 = (w8 + 8 * s) * 2;
        Vt[f2 * 72 + vm]       = vreg[s][0];
        Vt[(f2 + 1) * 72 + vm] = vreg[s][1];
      }
    }
    if (kt < 7) {
      const _Float16* Kn = Kg + (kt + 1) * 64 * 80;
      const _Float16* Vn = Vg + (kt + 1) * 64 * 80;
      int i0 = tid, r0 = i0 / 10, w0 = i0 - r0 * 10;
      kreg0 = *reinterpret_cast<const f16x8*>(Kn + r0 * 80 + w0 * 8);
      if (tid < 128) {
        int i1 = tid + 512, r1 = i1 / 10, w1 = i1 - r1 * 10;
        kreg1 = *reinterpret_cast<const f16x8*>(Kn + r1 * 80 + w1 * 8);
      }
      #pragma unroll
      for (int s = 0; s < 5; s++)
        vreg[s] = *reinterpret_cast<const f16x2*>(Vn + vm * 80 + (w8 + 8 * s) * 2);
    }
    __syncthreads();                 // LDS tile ready

    f32x4 S[4];
    #pragma unroll
    for (int ms = 0; ms < 4; ms++)
      #pragma unroll
      for (int r = 0; r < 4; r++) S[ms][r] = 0.f;
    __builtin_amdgcn_s_setprio(1);
    #pragma unroll
    for (int kc = 0; kc < 3; kc++) {
      #pragma unroll
      for (int ms = 0; ms < 4; ms++) {
        f16x8 kf = *reinterpret_cast<const f16x8*>(&Ks[(ms * 16 + lr) * 104 + kc * 32 + lg * 8]);
        S[ms] = __builtin_amdgcn_mfma_f32_16x16x32_f16(qf[kc], kf, S[ms], 0, 0, 0);
      }
    }
    __builtin_amdgcn_s_setprio(0);

    // fixed-max softmax numerator: p = exp(s - MFIX); no reductions, no rescale
    _Float16* pw = &Pl[w8 * 16 * 72];
    #pragma unroll
    for (int r = 0; r < 4; r++) {
      int row = lg * 4 + r;
      #pragma unroll
      for (int ms = 0; ms < 4; ms++)
        pw[row * 72 + ((ms * 16 + lr) ^ (lg << 3))] = (_Float16)__expf(S[ms][r] - MFIX);
    }
    asm volatile("s_waitcnt lgkmcnt(0)" ::: "memory");
    const int sx = (lg ^ ((lr >> 2) & 3)) * 8;
    f16x8 pf0 = *reinterpret_cast<const f16x8*>(&pw[lr * 72 + sx]);
    f16x8 pf1 = *reinterpret_cast<const f16x8*>(&pw[lr * 72 + 32 + sx]);

    __builtin_amdgcn_s_setprio(1);
    #pragma unroll
    for (int ft = 0; ft < 6; ft++) {
      f16x8 vf0 = *reinterpret_cast<const f16x8*>(&Vt[(ft * 16 + lr) * 72 + lg * 8]);
      f16x8 vf1 = *reinterpret_cast<const f16x8*>(&Vt[(ft * 16 + lr) * 72 + 32 + lg * 8]);
      O[ft] = __builtin_amdgcn_mfma_f32_16x16x32_f16(pf0, vf0, O[ft], 0, 0, 0);
      O[ft] = __builtin_amdgcn_mfma_f32_16x16x32_f16(pf1, vf1, O[ft], 0, 0, 0);
    }
    __builtin_amdgcn_s_setprio(0);
  }

  // epilogue: l for row lg*4+r sits in lane (lg*16 + 0), component r
  float inv[4];
  #pragma unroll
  for (int r = 0; r < 4; r++) {
    float l = __shfl(O[5][r], lg << 4);
    inv[r] = 1.f / l;
  }
  #pragma unroll
  for (int r = 0; r < 4; r++) {
    int t = t0 + w8 * 16 + lg * 4 + r;
    size_t base = ((size_t)(b * 128 + 64 + c) * TDIM + t) * FDIM;
    #pragma unroll
    for (int ft = 0; ft < 5; ft++)
      CAT[base + ft * 16 + lr] = (_Float16)(O[ft][r] * inv[r]);
  }
}

// ---------------- time attention via MFMA: per (b,c); writes CAT2 channel c plane ----------------
__global__ __launch_bounds__(256) void k_attn_time(
    const _Float16* __restrict__ XQ, const _Float16* __restrict__ XK,
    const _Float16* __restrict__ XV, _Float16* __restrict__ CAT)
{
  __shared__ __align__(16) char smem[70400];
  _Float16* Qt  = (_Float16*)smem;              // [80][136] phase1
  _Float16* Kt  = Qt + 80 * 136;                // [80][136]
  float*    Sld = (float*)(smem + 43520);       // [80][84] fp32 scores
  _Float16* Pld = (_Float16*)smem;              // [80][104] phase2 (aliases Qt, post-barrier)

  const int bid = blockIdx.x;                   // 512 blocks = (b,c)
  const int b = bid >> 6, c = bid & 63;
  const int tid = threadIdx.x;
  const int wv = tid >> 6, ln = tid & 63;
  const int lr = ln & 15, lg = ln >> 4;
  const float tscale = 0.04419417382415922f;    // 1/sqrt(512)

  const _Float16* Qg = XQ + (size_t)bid * 40960;
  const _Float16* Kg = XK + (size_t)bid * 40960;
  const _Float16* Vg = XV + (size_t)bid * 40960;

  f32x4 sacc[7];
  #pragma unroll
  for (int i = 0; i < 7; i++)
    #pragma unroll
    for (int r = 0; r < 4; r++) sacc[i][r] = 0.f;

  for (int tc = 0; tc < 4; tc++) {
    __syncthreads();
    for (int idx = tid; idx < 640; idx += 256) {
      int t2 = idx / 10, f8 = idx - t2 * 10;
      int tg = tc * 128 + t2 * 2;
      f16x8 qa = *reinterpret_cast<const f16x8*>(Qg + (size_t)tg * 80 + f8 * 8);
      f16x8 qb = *reinterpret_cast<const f16x8*>(Qg + (size_t)(tg + 1) * 80 + f8 * 8);
      f16x8 ka = *reinterpret_cast<const f16x8*>(Kg + (size_t)tg * 80 + f8 * 8);
      f16x8 kb = *reinterpret_cast<const f16x8*>(Kg + (size_t)(tg + 1) * 80 + f8 * 8);
      #pragma unroll
      for (int j = 0; j < 8; j++) {
        int f = f8 * 8 + j;
        f16x2 qp; qp[0] = qa[j]; qp[1] = qb[j];
        f16x2 kp; kp[0] = ka[j]; kp[1] = kb[j];
        *reinterpret_cast<f16x2*>(&Qt[f * 136 + t2 * 2]) = qp;
        *reinterpret_cast<f16x2*>(&Kt[f * 136 + t2 * 2]) = kp;
      }
    }
    __syncthreads();
    #pragma unroll
    for (int i = 0; i < 7; i++) {
      int ti = wv * 7 + i;
      int te = ti < 25 ? ti : 24;
      int mi = te / 5, ni = te - mi * 5;
      #pragma unroll
      for (int kc = 0; kc < 4; kc++) {
        f16x8 aq = *reinterpret_cast<const f16x8*>(&Qt[(mi * 16 + lr) * 136 + kc * 32 + lg * 8]);
        f16x8 bk = *reinterpret_cast<const f16x8*>(&Kt[(ni * 16 + lr) * 136 + kc * 32 + lg * 8]);
        sacc[i] = __builtin_amdgcn_mfma_f32_16x16x32_f16(aq, bk, sacc[i], 0, 0, 0);
      }
    }
  }
  #pragma unroll
  for (int i = 0; i < 7; i++) {
    int ti = wv * 7 + i;
    if (ti < 25) {
      int mi = ti / 5, ni = ti - mi * 5;
      #pragma unroll
      for (int r = 0; r < 4; r++)
        Sld[(mi * 16 + lg * 4 + r) * 84 + ni * 16 + lr] = sacc[i][r] * tscale;
    }
  }
  __syncthreads();

  {
    const int fy = tid >> 4, gx = tid & 15;
    #pragma unroll
    for (int pass = 0; pass < 5; pass++) {
      int row = pass * 16 + fy;
      float s[5];
      #pragma unroll
      for (int j = 0; j < 5; j++) s[j] = Sld[row * 84 + gx + 16 * j];
      float mx = fmaxf(fmaxf(fmaxf(s[0], s[1]), fmaxf(s[2], s[3])), s[4]);
      #pragma unroll
      for (int sh = 1; sh < 16; sh <<= 1) mx = fmaxf(mx, __shfl_xor(mx, sh, 16));
      float e[5]; float ls = 0.f;
      #pragma unroll
      for (int j = 0; j < 5; j++) { e[j] = __expf(s[j] - mx); ls += e[j]; }
      #pragma unroll
      for (int sh = 1; sh < 16; sh <<= 1) ls += __shfl_xor(ls, sh, 16);
      float inv = 1.f / ls;
      #pragma unroll
      for (int j = 0; j < 5; j++)
        Pld[row * 104 + gx + 16 * j] = (_Float16)(e[j] * inv);
    }
    for (int idx = tid; idx < 240; idx += 256) {
      int row = idx / 3, cw = idx - row * 3;
      f16x8 z;
      #pragma unroll
      for (int j = 0; j < 8; j++) z[j] = (_Float16)0.f;
      *reinterpret_cast<f16x8*>(&Pld[row * 104 + 80 + cw * 8]) = z;
    }
  }
  __syncthreads();

  f16x8 pa[5][3];
  #pragma unroll
  for (int mi = 0; mi < 5; mi++)
    #pragma unroll
    for (int kc = 0; kc < 3; kc++)
      pa[mi][kc] = *reinterpret_cast<const f16x8*>(&Pld[(mi * 16 + lr) * 104 + kc * 32 + lg * 8]);

  _Float16* Ow = (_Float16*)(smem + 43520) + wv * (16 * 88);  // per-wave [16 t][88 f] (Sld dead)
  const size_t chbase = (size_t)(b * 128 + c) * TDIM * FDIM;

  #pragma unroll
  for (int j = 0; j < 8; j++) {
    int nt = wv * 8 + j;
    f16x8 vf[3];
    #pragma unroll
    for (int kc = 0; kc < 3; kc++) {
      if (kc < 2) {
        vf[kc] = *reinterpret_cast<const f16x8*>(Vg + (size_t)(nt * 16 + lr) * 80 + kc * 32 + lg * 8);
      } else {
        f16x8 z;
        #pragma unroll
        for (int qq = 0; qq < 8; qq++) z[qq] = (_Float16)0.f;
        vf[kc] = (lg < 2) ? *reinterpret_cast<const f16x8*>(Vg + (size_t)(nt * 16 + lr) * 80 + 64 + lg * 8) : z;
      }
    }
    f32x4 oacc[5];
    #pragma unroll
    for (int mi = 0; mi < 5; mi++)
      #pragma unroll
      for (int r = 0; r < 4; r++) oacc[mi][r] = 0.f;
    #pragma unroll
    for (int mi = 0; mi < 5; mi++)
      #pragma unroll
      for (int kc = 0; kc < 3; kc++)
        oacc[mi] = __builtin_amdgcn_mfma_f32_16x16x32_f16(pa[mi][kc], vf[kc], oacc[mi], 0, 0, 0);

    #pragma unroll
    for (int mi = 0; mi < 5; mi++) {
      f16x4 h;
      #pragma unroll
      for (int r = 0; r < 4; r++) h[r] = (_Float16)oacc[mi][r];
      *reinterpret_cast<f16x4*>(&Ow[lr * 88 + mi * 16 + lg * 4]) = h;
    }
    asm volatile("s_waitcnt lgkmcnt(0)" ::: "memory");
    size_t basec = chbase + (size_t)(nt * 16) * FDIM;
    #pragma unroll
    for (int kk2 = 0; kk2 < 3; kk2++) {
      int idx = ln + (kk2 << 6);
      if (idx < 160) {
        int tl2 = idx / 10, f8 = idx - tl2 * 10;
        *reinterpret_cast<f16x8*>(CAT + basec + tl2 * 80 + f8 * 8) =
            *reinterpret_cast<const f16x8*>(&Ow[tl2 * 88 + f8 * 8]);
      }
    }
  }
}

// ---------------- conv 3x3 128->64, t-PAIR + two-phase ci (512 thr), batched staging ----------------
__global__ __launch_bounds__(512) void k_conv_out(
    const _Float16* __restrict__ x, const float* __restrict__ w,
    const _Float16* __restrict__ wT,
    const float* __restrict__ bias, float* __restrict__ out)
{
  __shared__ __align__(16) _Float16 xs[328 * 72];   // [rr*82+fi][ci 64 of current phase]
  const int bid = blockIdx.x;                       // 2048
  const int xcd = bid & 7, i = bid >> 3;            // i 0..255
  const int b = i >> 5, tp = i & 31;
  const int t0 = (xcd << 6) | (tp << 1);
  const int tid = threadIdx.x;
  const int wvv = tid >> 6, ln = tid & 63;
  const int tsel = wvv >> 2;                        // 0: t0, 1: t0+1
  const int lr = ln & 15, lg = ln >> 4;
  const int c0 = (wvv & 3) * 16;
  const int t = t0 + tsel;

  float bv = bias[c0 + lr];
  f32x4 acc[5];
  #pragma unroll
  for (int mt = 0; mt < 5; mt++)
    #pragma unroll
    for (int r = 0; r < 4; r++) acc[mt][r] = bv;

  const _Float16* xb = x + (size_t)b * 128 * TDIM * FDIM;

  for (int h = 0; h < 2; h++) {
    __syncthreads();                                // prior phase's reads complete
    {
      int cch = tid & 63, sk = tid >> 6;            // sk 0..7
      int rr = sk >> 1, side = sk & 1;
      xs[(rr * 82 + side * 81) * 72 + cch] = (_Float16)0.f;
    }
    f16x8 hb[5];
    #pragma unroll
    for (int kk = 0; kk < 5; kk++) {
      int idx = tid + (kk << 9);                    // 0..2559
      int cch = idx & 63, rest = idx >> 6;          // rest 0..39
      int rr = rest / 10, f8 = rest - rr * 10;
      int tt = t0 - 1 + rr;
      #pragma unroll
      for (int j = 0; j < 8; j++) hb[kk][j] = (_Float16)0.f;
      if (tt >= 0 && tt < TDIM)
        hb[kk] = *reinterpret_cast<const f16x8*>(xb + ((size_t)(h * 64 + cch) * TDIM + tt) * FDIM + f8 * 8);
    }
    #pragma unroll
    for (int kk = 0; kk < 5; kk++) {
      int idx = tid + (kk << 9);
      int cch = idx & 63, rest = idx >> 6;
      int rr = rest / 10, f8 = rest - rr * 10;
      #pragma unroll
      for (int j = 0; j < 8; j++)
        xs[(rr * 82 + f8 * 8 + j + 1) * 72 + cch] = hb[kk][j];
    }
    __syncthreads();

    for (int ky = 0; ky < 3; ky++) {
      const int rr = tsel + ky;                     // row t+ky-1 lives at slot rr
      f16x8 wf[3][2];
      #pragma unroll
      for (int kx = 0; kx < 3; kx++)
        #pragma unroll
        for (int cc = 0; cc < 2; cc++) {
          if (wT) {
            wf[kx][cc] = *reinterpret_cast<const f16x8*>(
                wT + (((ky * 3 + kx) * 64 + c0 + lr) << 7) + h * 64 + cc * 32 + lg * 8);
          } else {
            const float* wp = w + ((ky * 3 + kx) * 128 + h * 64 + cc * 32 + lg * 8) * 64 + c0 + lr;
            #pragma unroll
            for (int j = 0; j < 8; j++) wf[kx][cc][j] = (_Float16)wp[j * 64];
          }
        }
      #pragma unroll
      for (int mt = 0; mt < 5; mt++) {
        #pragma unroll
        for (int kx = 0; kx < 3; kx++) {
          const _Float16* ap = &xs[(rr * 82 + mt * 16 + lr + kx) * 72];
          #pragma unroll
          for (int cc = 0; cc < 2; cc++) {
            f16x8 af = *reinterpret_cast<const f16x8*>(ap + cc * 32 + lg * 8);
            acc[mt] = __builtin_amdgcn_mfma_f32_16x16x32_f16(af, wf[kx][cc], acc[mt], 0, 0, 0);
          }
        }
      }
    }
  }

  const int c = c0 + lr;
  #pragma unroll
  for (int mt = 0; mt < 5; mt++) {
    #pragma unroll
    for (int r = 0; r < 4; r++) {
      int f = mt * 16 + lg * 4 + r;
      out[((size_t)(b * TDIM + t) * FDIM + f) * 64 + c] = acc[mt][r];
    }
  }
}

extern "C" void kernel_launch(void* const* d_in, const int* in_sizes, int n_in,
                              void* d_out, int out_size, void* d_ws, size_t ws_size,
                              hipStream_t stream)
{
  const float* q  = (const float*)d_in[0];
  const float* k  = (const float*)d_in[1];
  const float* v  = (const float*)d_in[2];
  const float* wq = (const float*)d_in[3];
  const float* bq = (const float*)d_in[4];
  const float* wk = (const float*)d_in[5];
  const float* bk = (const float*)d_in[6];
  const float* wv = (const float*)d_in[7];
  const float* bv = (const float*)d_in[8];
  const float* wo = (const float*)d_in[9];
  const float* bo = (const float*)d_in[10];

  const size_t PLANE = (size_t)8 * 64 * 512 * 80;   // 20,971,520 elements
  _Float16* XQh  = (_Float16*)d_ws;
  _Float16* XKh  = XQh + PLANE;
  _Float16* CATh = XKh + PLANE;                     // CAT2 [B][128][T][F] fp16
  _Float16* XVh  = (_Float16*)d_out;                // dead before k_conv_out writes

  // optional fp16-transposed weights after CAT (needs 368 KB beyond the 168 MB base)
  _Float16* WT = CATh + 2 * PLANE;
  const size_t need = (4 * PLANE + 184320) * sizeof(_Float16);
  const bool useWT = (ws_size >= need);
  _Float16* wTq = useWT ? WT : nullptr;             // 36864 halves each
  _Float16* wTk = useWT ? WT + 36864 : nullptr;
  _Float16* wTv = useWT ? WT + 73728 : nullptr;
  _Float16* wTo = useWT ? WT + 110592 : nullptr;    // 73728 halves

  if (useWT)
    hipLaunchKernelGGL(k_prep_w, dim3(180), dim3(256), 0, stream,
                       wq, wk, wv, wo, wTq, wTk, wTv, wTo);

  hipLaunchKernelGGL(k_conv_in3, dim3(6144), dim3(512), 0, stream,
                     q, k, v, wq, wk, wv, wTq, wTk, wTv, bq, bk, bv, XQh, XKh, XVh);
  hipLaunchKernelGGL(k_attn_freq, dim3(2048), dim3(512), 0, stream, XQh, XKh, XVh, CATh);
  hipLaunchKernelGGL(k_attn_time, dim3(512), dim3(256), 0, stream, XQh, XKh, XVh, CATh);
  hipLaunchKernelGGL(k_conv_out, dim3(2048), dim3(512), 0, stream, CATh, wo, wTo, bo, (float*)d_out);
}